// Round 6
// baseline (110.403 us; speedup 1.0000x reference)
//
#include <hip/hip_runtime.h>
#include <cstdint>
#include <cstddef>

// Problem dims
#define B_ROWS 65536
#define D_IN   784
#define KP     800      // D_IN padded to multiple of 32
#define D_H    300
#define NP     320      // D_H padded to multiple of 64
#define D_OUT  10
#define NP2    16       // D_OUT padded to 16
#define EPS    1e-5f
#define NBLK   1024     // blocks in gemm1 and gemm2 grids
#define APAD   44       // LDS A row stride in halfs (44*2=88 B -> <=2-way banks)

typedef _Float16 half8  __attribute__((ext_vector_type(8)));
typedef float    floatx4 __attribute__((ext_vector_type(4)));

// Workspace layout (bytes). part[] aliases oc[]: part is consumed by k_stat1
// BEFORE k_gemm2 writes oc (strictly ordered on one stream).
#define OFF_S1   ((size_t)0)                       // _Float16[320*800]   = 512000
#define OFF_H    ((size_t)512000)                  // _Float16[65536*320] = 41943040
#define OFF_ST1  (OFF_H + (size_t)41943040)        // float[640] (unused, layout keep)
#define OFF_W2   (OFF_ST1 + (size_t)2560)          // _Float16[16*320]    = 10240
#define OFF_ST2  (OFF_W2 + (size_t)10240)          // float[32]
#define OFF_OC   (OFF_ST2 + (size_t)256)           // float[65536*16]     = 4194304
#define OFF_P1   OFF_OC                            // float[640][1024] (alias, time-disjoint)
#define OFF_P2   (OFF_OC + (size_t)4194304)        // float[32][1024]     = 131072

// ---------------- K0: binarize W1 -> fp16 (+-1), zero-padded to [320][800]
__global__ void k_prep1(const float* __restrict__ W1, _Float16* __restrict__ S1)
{
    int idx = blockIdx.x * 256 + threadIdx.x;      // 0..255999
    int n = idx / KP;
    int k = idx - n * KP;
    float v = 0.0f;
    if (n < D_H && k < D_IN)
        v = (W1[n * D_IN + k] >= 0.0f) ? 1.0f : -1.0f;
    S1[idx] = (_Float16)v;
}

// ---------------- K1: h = x @ S1^T  (M=65536, N=320, K=800), fp16 MFMA
// FINE PHASE-SPLIT variant (T3-fine + T5). Dataflow identical to the proven
// R0/R2 skeleton: A staged once/block (fp32 load -> cvt -> fp16 ds_write)
// into double-buffered stride-44 LDS; B ping-ponged in registers from L2;
// depth-2 x register prefetch; ONE raw barrier per 32-wide K-step (no vmcnt
// drain). NEW: each step's 20 MFMA are split into two 10-MFMA clusters,
// each preceded by {its own 2 ds_reads || one class of global-load issue},
// fenced with lgkmcnt(0)+sched_barrier, and wrapped in s_setprio(1/0).
// Rationale: m196 showed coarse phase-splits (our R2/R3) are null-to-worse
// while the fine ds_read||G-load||MFMA interleave is the lever; T5 pays
// only once a phase-split creates wave role-diversity (m218b/m224).
// Accumulation order per acc[][] is unchanged (one MFMA per step each) ->
// numerics bit-identical.

#define PF_B(BV, NK)                                                        \
    _Pragma("unroll")                                                       \
    for (int nt = 0; nt < 5; ++nt)                                          \
        BV[nt] = *(const half8*)(bb + (size_t)nt * 16 * KP + (NK));

#define STAGE_LOAD(V0, V1, KK)                                              \
    {                                                                       \
        V0 = (floatx4){}; V1 = (floatx4){};                                 \
        if ((KK) + sc < D_IN) {            /* chunk-uniform: D_IN%8==0 */   \
            V0 = *(const floatx4*)(sxp + (KK));                             \
            V1 = *(const floatx4*)(sxp + (KK) + 4);                         \
        }                                                                   \
    }

#define STAGE_STORE(V0, V1, BUF)                                            \
    {                                                                       \
        half8 hv;                                                           \
        _Pragma("unroll")                                                   \
        for (int i2 = 0; i2 < 4; ++i2) {                                    \
            hv[i2]     = (_Float16)V0[i2];                                  \
            hv[4 + i2] = (_Float16)V1[i2];                                  \
        }                                                                   \
        *(half8*)&Alds[BUF][srow][sc] = hv;                                 \
    }

// half-H of the A fragments (mt = 2H, 2H+1)
#define AFRAG_H(BUF, H)                                                     \
    _Pragma("unroll")                                                       \
    for (int mt = 2 * (H); mt < 2 * (H) + 2; ++mt)                          \
        a[mt] = *(const half8*)&Alds[BUF][mt * 16 + row15][quad * 8];

// half-H of the MFMA cluster (10 MFMA), setprio-wrapped
#define COMPUTE_H(BV, H)                                                    \
    __builtin_amdgcn_s_setprio(1);                                          \
    _Pragma("unroll")                                                       \
    for (int nt = 0; nt < 5; ++nt)                                          \
        _Pragma("unroll")                                                   \
        for (int mt = 2 * (H); mt < 2 * (H) + 2; ++mt)                      \
            acc[mt][nt] = __builtin_amdgcn_mfma_f32_16x16x32_f16(           \
                a[mt], BV[nt], acc[mt][nt], 0, 0, 0);                       \
    __builtin_amdgcn_s_setprio(0);

// ds ops done; fence so MFMA can't hoist above the wait (rule 18)
#define LGKM0()                                                             \
    asm volatile("s_waitcnt lgkmcnt(0)" ::: "memory");                      \
    __builtin_amdgcn_sched_barrier(0);

// end-of-step publish: raw barrier, NO vmcnt drain (in-flight loads survive)
#define BARRIER()                                                           \
    __builtin_amdgcn_sched_barrier(0);                                      \
    __builtin_amdgcn_s_barrier();                                           \
    __builtin_amdgcn_sched_barrier(0);

__global__ __launch_bounds__(256) void k_gemm1(const float* __restrict__ x,
                                               const _Float16* __restrict__ S1,
                                               _Float16* __restrict__ h,
                                               float* __restrict__ part)
{
    __shared__ _Float16 Alds[2][64][APAD];   // 2 x 5.5 KB
    const int t     = threadIdx.x;
    const int wave  = t >> 6;
    const int lane  = t & 63;
    const int row15 = lane & 15;
    const int quad  = lane >> 4;
    const int m0    = blockIdx.x * 64;

    // staging assignment: thread t -> row t>>2, half-chunk (t&3)*8
    const int srow = t >> 2;
    const int sc   = (t & 3) * 8;
    const float* sxp = x + (size_t)(m0 + srow) * D_IN + sc;

    // B fragment base (MFMA B layout: lane holds col=row15, k=quad*8..+8)
    const _Float16* bb = S1 + (size_t)(wave * 80 + row15) * KP + quad * 8;

    floatx4 acc[4][5] = {};
    half8   b0[5], b1[5];
    half8   a[4];
    floatx4 a0, a1, c0, c1;      // depth-2 x prefetch register sets

    // prologue: buf0 <- x(0); svB(c) <- x(1) in flight; b0 <- B(0)
    STAGE_LOAD(a0, a1, 0)
    PF_B(b0, 0)
    STAGE_LOAD(c0, c1, 32)
    STAGE_STORE(a0, a1, 0)       // counted vmcnt: waits only x(0)
    LGKM0()
    BARRIER()

    for (int i = 0; i < 12; ++i) {
        const int kk = i * 64;
        // ---- even step s=2i: reads buf0/b0; svB holds x(s+1)
        // phase 1: ds_read half-A || issue x(s+2); MFMA half 1
        AFRAG_H(0, 0)
        STAGE_LOAD(a0, a1, kk + 64)
        LGKM0()
        COMPUTE_H(b0, 0)
        // phase 2: ds_read half-A || issue B(s+1) + stage x(s+1); MFMA half 2
        AFRAG_H(0, 1)
        PF_B(b1, kk + 32)
        STAGE_STORE(c0, c1, 1)   // waits x(s+1) loads, issued one step ago
        LGKM0()
        COMPUTE_H(b0, 1)
        BARRIER()
        // ---- odd step s=2i+1: reads buf1/b1; svA holds x(s+1)
        AFRAG_H(1, 0)
        STAGE_LOAD(c0, c1, kk + 96)   // i=11 -> 800: guard kills all loads
        LGKM0()
        COMPUTE_H(b1, 0)
        AFRAG_H(1, 1)
        PF_B(b0, kk + 64)             // i=11 -> B(24) at koff 768
        STAGE_STORE(a0, a1, 0)
        LGKM0()
        COMPUTE_H(b1, 1)
        BARRIER()
    }
    // tail step 24: reads buf0/b0 (k = 768..799, pad lanes hit B zeros)
    AFRAG_H(0, 0)
    LGKM0()
    COMPUTE_H(b0, 0)
    AFRAG_H(0, 1)
    LGKM0()
    COMPUTE_H(b0, 1)

    // --- epilogue: store h (C/D layout: col=lane&15, row=quad*4+r) + stats
    float s[5] = {}, q[5] = {};
#pragma unroll
    for (int mt = 0; mt < 4; ++mt)
#pragma unroll
        for (int nt = 0; nt < 5; ++nt)
#pragma unroll
            for (int r = 0; r < 4; ++r) {
                float v = acc[mt][nt][r];
                int m = m0 + mt * 16 + quad * 4 + r;
                int n = wave * 80 + nt * 16 + row15;
                h[(size_t)m * NP + n] = (_Float16)v;
                s[nt] += v;
                q[nt] += v * v;
            }
    // reduce over quad (waves own disjoint col ranges -> no cross-wave combine)
#pragma unroll
    for (int nt = 0; nt < 5; ++nt) {
        s[nt] += __shfl_xor(s[nt], 16); s[nt] += __shfl_xor(s[nt], 32);
        q[nt] += __shfl_xor(q[nt], 16); q[nt] += __shfl_xor(q[nt], 32);
    }
    if (quad == 0) {
#pragma unroll
        for (int nt = 0; nt < 5; ++nt) {
            int col = wave * 80 + nt * 16 + row15;
            part[(size_t)col * NBLK + blockIdx.x]        = s[nt];
            part[(size_t)(NP + col) * NBLK + blockIdx.x] = q[nt];
        }
    }
}

// ---------------- K2: FUSED reduce + BN1-fold-into-W2
// One block per hidden col j: reduce sum AND sumsq partials, then threads
// 0..15 write the BN1-scaled binarized W2 column.
__global__ void k_stat1(const float* __restrict__ part, const float* __restrict__ gamma1,
                        const float* __restrict__ W2, _Float16* __restrict__ w2h)
{
    __shared__ float redS[4], redQ[4];
    const int j = blockIdx.x;            // 0..319
    const int t = threadIdx.x;           // 256
    const float* ps = part + (size_t)j * NBLK;
    const float* pq = part + (size_t)(NP + j) * NBLK;
    float s = ps[t] + ps[t + 256] + ps[t + 512] + ps[t + 768];
    float q = pq[t] + pq[t + 256] + pq[t + 512] + pq[t + 768];
#pragma unroll
    for (int off = 1; off < 64; off <<= 1) {
        s += __shfl_xor(s, off);
        q += __shfl_xor(q, off);
    }
    if ((t & 63) == 0) { redS[t >> 6] = s; redQ[t >> 6] = q; }
    __syncthreads();
    if (t < NP2) {
        float S = redS[0] + redS[1] + redS[2] + redS[3];
        float Q = redQ[0] + redQ[1] + redQ[2] + redQ[3];
        float mean = S * (1.0f / 65536.0f);
        float var  = Q * (1.0f / 65536.0f) - mean * mean;
        float a1   = 0.0f;
        if (j < D_H) a1 = gamma1[j] / sqrtf(var + EPS);
        float w = 0.0f;
        if (t < D_OUT && j < D_H)
            w = (W2[t * D_H + j] >= 0.0f) ? a1 : -a1;
        w2h[t * NP + j] = (_Float16)w;
    }
}

// ---------------- K3: oc = h @ w2h^T  (K=320, N=16) + per-block stat partials
__global__ __launch_bounds__(256) void k_gemm2(const _Float16* __restrict__ h,
                                               const _Float16* __restrict__ w2h,
                                               float* __restrict__ oc,
                                               float* __restrict__ part2)
{
    __shared__ _Float16 Wlds[16][328];   // pad 320->328 to break bank conflicts
    __shared__ float reds[4][16], redq[4][16];
    const int t     = threadIdx.x;
    const int wave  = t >> 6;
    const int lane  = t & 63;
    const int row15 = lane & 15;
    const int quad  = lane >> 4;

    for (int c = t; c < 640; c += 256) { // 16*320/8 chunks
        int r  = c / 40;
        int cc = (c - r * 40) * 8;
        *(half8*)&Wlds[r][cc] = *(const half8*)(w2h + r * NP + cc);
    }
    __syncthreads();

    const int m0 = blockIdx.x * 64 + wave * 16;
    const _Float16* hp = h + (size_t)(m0 + row15) * NP + quad * 8;
    floatx4 acc = {};
#pragma unroll
    for (int kk = 0; kk < NP; kk += 32) {
        half8 a2 = *(const half8*)(hp + kk);
        half8 b2 = *(const half8*)&Wlds[row15][kk + quad * 8];
        acc = __builtin_amdgcn_mfma_f32_16x16x32_f16(a2, b2, acc, 0, 0, 0);
    }
    float s = 0.f, q = 0.f;
#pragma unroll
    for (int r = 0; r < 4; ++r) {
        float v = acc[r];
        oc[(size_t)(m0 + quad * 4 + r) * NP2 + row15] = v;
        s += v; q += v * v;
    }
    s += __shfl_xor(s, 16); s += __shfl_xor(s, 32);
    q += __shfl_xor(q, 16); q += __shfl_xor(q, 32);
    if (lane < 16) { reds[wave][row15] = s; redq[wave][row15] = q; }
    __syncthreads();
    if (t < 16) {
        float S = reds[0][t] + reds[1][t] + reds[2][t] + reds[3][t];
        float Q = redq[0][t] + redq[1][t] + redq[2][t] + redq[3][t];
        part2[(size_t)t * NBLK + blockIdx.x]          = S;
        part2[(size_t)(16 + t) * NBLK + blockIdx.x]   = Q;
    }
}

// ---------------- K4: FUSED reduce#2 + BN2-coefficient precompute
__global__ void k_stat2(const float* __restrict__ part2, const float* __restrict__ gamma2,
                        float* __restrict__ st2)
{
    __shared__ float redS[4], redQ[4];
    const int k = blockIdx.x;            // 0..15
    const int t = threadIdx.x;           // 256
    const float* ps = part2 + (size_t)k * NBLK;
    const float* pq = part2 + (size_t)(16 + k) * NBLK;
    float s = ps[t] + ps[t + 256] + ps[t + 512] + ps[t + 768];
    float q = pq[t] + pq[t + 256] + pq[t + 512] + pq[t + 768];
#pragma unroll
    for (int off = 1; off < 64; off <<= 1) {
        s += __shfl_xor(s, off);
        q += __shfl_xor(q, off);
    }
    if ((t & 63) == 0) { redS[t >> 6] = s; redQ[t >> 6] = q; }
    __syncthreads();
    if (t == 0) {
        float S = redS[0] + redS[1] + redS[2] + redS[3];
        float Q = redQ[0] + redQ[1] + redQ[2] + redQ[3];
        float mean = S * (1.0f / 65536.0f);
        float var  = Q * (1.0f / 65536.0f) - mean * mean;
        float sc   = (k < D_OUT) ? gamma2[k] / sqrtf(var + EPS) : 0.0f;
        st2[k]      = mean;
        st2[16 + k] = sc;
    }
}

// ---------------- K5: BN2 epilogue -> out[65536][10] fp32
__global__ void k_final(const float* __restrict__ oc, const float* __restrict__ st2,
                        const float* __restrict__ beta2, float* __restrict__ out)
{
    int idx = blockIdx.x * 256 + threadIdx.x;    // 2560*256 == 655360 exactly
    int m = idx / 10;
    int k = idx - m * 10;
    float mean = st2[k];
    float sc   = st2[16 + k];
    out[idx] = (oc[(size_t)m * NP2 + k] - mean) * sc + beta2[k];
}

extern "C" void kernel_launch(void* const* d_in, const int* in_sizes, int n_in,
                              void* d_out, int out_size, void* d_ws, size_t ws_size,
                              hipStream_t stream)
{
    const float* x      = (const float*)d_in[0];
    const float* W1     = (const float*)d_in[1];
    const float* gamma1 = (const float*)d_in[2];
    // d_in[3] = beta1 : algebraically cancels under BN2's mean subtraction
    const float* W2     = (const float*)d_in[4];
    const float* gamma2 = (const float*)d_in[5];
    const float* beta2  = (const float*)d_in[6];
    float* out = (float*)d_out;

    char* ws = (char*)d_ws;
    _Float16* S1    = (_Float16*)(ws + OFF_S1);
    _Float16* h     = (_Float16*)(ws + OFF_H);
    _Float16* w2h   = (_Float16*)(ws + OFF_W2);
    float*    st2   = (float*)(ws + OFF_ST2);
    float*    oc    = (float*)(ws + OFF_OC);
    float*    part  = (float*)(ws + OFF_P1);   // aliases oc (time-disjoint)
    float*    part2 = (float*)(ws + OFF_P2);

    k_prep1 <<<1000, 256, 0, stream>>>(W1, S1);
    k_gemm1 <<<NBLK, 256, 0, stream>>>(x, S1, h, part);
    k_stat1 <<<320, 256, 0, stream>>>(part, gamma1, W2, w2h);
    k_gemm2 <<<NBLK, 256, 0, stream>>>(h, w2h, oc, part2);
    k_stat2 <<<16, 256, 0, stream>>>(part2, gamma2, st2);
    k_final <<<2560, 256, 0, stream>>>(oc, st2, beta2, out);
}

// Round 7
// 105.110 us; speedup vs baseline: 1.0504x; 1.0504x over previous
//
#include <hip/hip_runtime.h>
#include <cstdint>
#include <cstddef>

// Problem dims
#define B_ROWS 65536
#define D_IN   784
#define KP     800      // D_IN padded to multiple of 32
#define D_H    300
#define NP     320      // D_H padded to multiple of 64
#define D_OUT  10
#define NP2    16       // D_OUT padded to 16
#define EPS    1e-5f
#define NBLK   1024     // blocks in gemm1 and gemm2 grids
#define APAD   44       // LDS A row stride in halfs (44*2=88 B -> <=2-way banks)

typedef _Float16 half8  __attribute__((ext_vector_type(8)));
typedef float    floatx4 __attribute__((ext_vector_type(4)));

// Workspace layout (bytes). part[] aliases oc[]: part is consumed by k_stat1
// BEFORE k_gemm2 writes oc (strictly ordered on one stream).
#define OFF_S1   ((size_t)0)                       // _Float16[320*800]   = 512000
#define OFF_H    ((size_t)512000)                  // _Float16[65536*320] = 41943040
#define OFF_ST1  (OFF_H + (size_t)41943040)        // float[640] (unused, layout keep)
#define OFF_W2   (OFF_ST1 + (size_t)2560)          // _Float16[16*320]    = 10240
#define OFF_ST2  (OFF_W2 + (size_t)10240)          // float[32]
#define OFF_OC   (OFF_ST2 + (size_t)256)           // float[65536*16]     = 4194304
#define OFF_P1   OFF_OC                            // float[640][1024] (alias, time-disjoint)
#define OFF_P2   (OFF_OC + (size_t)4194304)        // float[32][1024]     = 131072

// ---------------- K0: binarize W1 -> fp16 (+-1), zero-padded to [320][800]
__global__ void k_prep1(const float* __restrict__ W1, _Float16* __restrict__ S1)
{
    int idx = blockIdx.x * 256 + threadIdx.x;      // 0..255999
    int n = idx / KP;
    int k = idx - n * KP;
    float v = 0.0f;
    if (n < D_H && k < D_IN)
        v = (W1[n * D_IN + k] >= 0.0f) ? 1.0f : -1.0f;
    S1[idx] = (_Float16)v;
}

// ---------------- K1: h = x @ S1^T  (M=65536, N=320, K=800), fp16 MFMA
// 3-BLOCKS/CU variant. Dataflow = the R0-proven skeleton bit-for-bit (A
// staged once/block fp32->cvt->fp16 into double-buffered stride-44 LDS,
// depth-1 in-step x prefetch, one barrier per 32-wide K-step), with two
// changes to fit a third co-resident block per CU (m114: implicit
// wave-level overlap at ~3 blocks/CU is what source-level pipelining
// couldn't add -- every explicit-pipeline variant R1-R6 measured null):
//  1. B single-buffered (drops b1[5] = 20 VGPRs): PF_B at step top,
//     consumed after AFRAG+lgkm wait (~300cy of cover for ~200cy L2 hit,
//     counted vmcnt, plus 12-wave TLP).
//  2. __launch_bounds__(256, 3): 3 waves/SIMD -> unified budget 170
//     (80 AGPR acc + ~85 arch).
// Raw lgkm-only barrier (R2-proven equal to __syncthreads) so the in-step
// x-prefetch survives the barrier. Numerics identical (same k order, RTNE).

#define PF_B(BV, NK)                                                        \
    _Pragma("unroll")                                                       \
    for (int nt = 0; nt < 5; ++nt)                                          \
        BV[nt] = *(const half8*)(bb + (size_t)nt * 16 * KP + (NK));

#define STAGE_LOAD(KK)                                                      \
    {                                                                       \
        sv0 = (floatx4){}; sv1 = (floatx4){};                               \
        if ((KK) + sc < D_IN) {            /* chunk-uniform: D_IN%8==0 */   \
            sv0 = *(const floatx4*)(sxp + (KK));                            \
            sv1 = *(const floatx4*)(sxp + (KK) + 4);                        \
        }                                                                   \
    }

#define STAGE_STORE(BUF)                                                    \
    {                                                                       \
        half8 hv;                                                           \
        _Pragma("unroll")                                                   \
        for (int i2 = 0; i2 < 4; ++i2) {                                    \
            hv[i2]     = (_Float16)sv0[i2];                                 \
            hv[4 + i2] = (_Float16)sv1[i2];                                 \
        }                                                                   \
        *(half8*)&Alds[BUF][srow][sc] = hv;                                 \
    }

#define AFRAG(BUF)                                                          \
    _Pragma("unroll")                                                       \
    for (int mt = 0; mt < 4; ++mt)                                          \
        a[mt] = *(const half8*)&Alds[BUF][mt * 16 + row15][quad * 8];

#define COMPUTE(BV)                                                         \
    _Pragma("unroll")                                                       \
    for (int nt = 0; nt < 5; ++nt)                                          \
        _Pragma("unroll")                                                   \
        for (int mt = 0; mt < 4; ++mt)                                      \
            acc[mt][nt] = __builtin_amdgcn_mfma_f32_16x16x32_f16(           \
                a[mt], BV[nt], acc[mt][nt], 0, 0, 0);

// Publish LDS writes WITHOUT draining vmcnt (in-flight x/B loads survive the
// barrier); sched fences pin memory ops on their side (rule 18).
#define BAR()                                                               \
    asm volatile("s_waitcnt lgkmcnt(0)" ::: "memory");                      \
    __builtin_amdgcn_sched_barrier(0);                                      \
    __builtin_amdgcn_s_barrier();                                           \
    __builtin_amdgcn_sched_barrier(0);

__global__ __launch_bounds__(256, 3) void k_gemm1(const float* __restrict__ x,
                                                  const _Float16* __restrict__ S1,
                                                  _Float16* __restrict__ h,
                                                  float* __restrict__ part)
{
    __shared__ _Float16 Alds[2][64][APAD];   // 2 x 5.5 KB
    const int t     = threadIdx.x;
    const int wave  = t >> 6;
    const int lane  = t & 63;
    const int row15 = lane & 15;
    const int quad  = lane >> 4;
    const int m0    = blockIdx.x * 64;

    // staging assignment: thread t -> row t>>2, half-chunk (t&3)*8
    const int srow = t >> 2;
    const int sc   = (t & 3) * 8;
    const float* sxp = x + (size_t)(m0 + srow) * D_IN + sc;

    // B fragment base (MFMA B layout: lane holds col=row15, k=quad*8..+8)
    const _Float16* bb = S1 + (size_t)(wave * 80 + row15) * KP + quad * 8;

    floatx4 acc[4][5] = {};
    half8   b[5];                // single-buffered B (was ping-pong: -20 VGPR)
    half8   a[4];
    floatx4 sv0, sv1;

    STAGE_LOAD(0)
    STAGE_STORE(0)
    BAR()

    for (int i = 0; i < 12; ++i) {
        const int kk = i * 64;
        // even step 2i: reads Alds[0]; B(2i) issued here, counted-vmcnt wait
        PF_B(b, kk)
        STAGE_LOAD(kk + 32)
        AFRAG(0)
        COMPUTE(b)
        STAGE_STORE(1)
        BAR()
        // odd step 2i+1: reads Alds[1]
        PF_B(b, kk + 32)
        STAGE_LOAD(kk + 64)            // i=11 -> 768 (tail chunks zero-padded)
        AFRAG(1)
        COMPUTE(b)
        STAGE_STORE(0)
        BAR()
    }
    // tail step 24: reads Alds[0] (k = 768..799, pad lanes hit B zeros)
    PF_B(b, 768)
    AFRAG(0)
    COMPUTE(b)

    // --- epilogue: store h (C/D layout: col=lane&15, row=quad*4+r) + stats
    float s[5] = {}, q[5] = {};
#pragma unroll
    for (int mt = 0; mt < 4; ++mt)
#pragma unroll
        for (int nt = 0; nt < 5; ++nt)
#pragma unroll
            for (int r = 0; r < 4; ++r) {
                float v = acc[mt][nt][r];
                int m = m0 + mt * 16 + quad * 4 + r;
                int n = wave * 80 + nt * 16 + row15;
                h[(size_t)m * NP + n] = (_Float16)v;
                s[nt] += v;
                q[nt] += v * v;
            }
    // reduce over quad (waves own disjoint col ranges -> no cross-wave combine)
#pragma unroll
    for (int nt = 0; nt < 5; ++nt) {
        s[nt] += __shfl_xor(s[nt], 16); s[nt] += __shfl_xor(s[nt], 32);
        q[nt] += __shfl_xor(q[nt], 16); q[nt] += __shfl_xor(q[nt], 32);
    }
    if (quad == 0) {
#pragma unroll
        for (int nt = 0; nt < 5; ++nt) {
            int col = wave * 80 + nt * 16 + row15;
            part[(size_t)col * NBLK + blockIdx.x]        = s[nt];
            part[(size_t)(NP + col) * NBLK + blockIdx.x] = q[nt];
        }
    }
}

// ---------------- K2: FUSED reduce + BN1-fold-into-W2
// One block per hidden col j: reduce sum AND sumsq partials, then threads
// 0..15 write the BN1-scaled binarized W2 column.
__global__ void k_stat1(const float* __restrict__ part, const float* __restrict__ gamma1,
                        const float* __restrict__ W2, _Float16* __restrict__ w2h)
{
    __shared__ float redS[4], redQ[4];
    const int j = blockIdx.x;            // 0..319
    const int t = threadIdx.x;           // 256
    const float* ps = part + (size_t)j * NBLK;
    const float* pq = part + (size_t)(NP + j) * NBLK;
    float s = ps[t] + ps[t + 256] + ps[t + 512] + ps[t + 768];
    float q = pq[t] + pq[t + 256] + pq[t + 512] + pq[t + 768];
#pragma unroll
    for (int off = 1; off < 64; off <<= 1) {
        s += __shfl_xor(s, off);
        q += __shfl_xor(q, off);
    }
    if ((t & 63) == 0) { redS[t >> 6] = s; redQ[t >> 6] = q; }
    __syncthreads();
    if (t < NP2) {
        float S = redS[0] + redS[1] + redS[2] + redS[3];
        float Q = redQ[0] + redQ[1] + redQ[2] + redQ[3];
        float mean = S * (1.0f / 65536.0f);
        float var  = Q * (1.0f / 65536.0f) - mean * mean;
        float a1   = 0.0f;
        if (j < D_H) a1 = gamma1[j] / sqrtf(var + EPS);
        float w = 0.0f;
        if (t < D_OUT && j < D_H)
            w = (W2[t * D_H + j] >= 0.0f) ? a1 : -a1;
        w2h[t * NP + j] = (_Float16)w;
    }
}

// ---------------- K3: oc = h @ w2h^T  (K=320, N=16) + per-block stat partials
__global__ __launch_bounds__(256) void k_gemm2(const _Float16* __restrict__ h,
                                               const _Float16* __restrict__ w2h,
                                               float* __restrict__ oc,
                                               float* __restrict__ part2)
{
    __shared__ _Float16 Wlds[16][328];   // pad 320->328 to break bank conflicts
    __shared__ float reds[4][16], redq[4][16];
    const int t     = threadIdx.x;
    const int wave  = t >> 6;
    const int lane  = t & 63;
    const int row15 = lane & 15;
    const int quad  = lane >> 4;

    for (int c = t; c < 640; c += 256) { // 16*320/8 chunks
        int r  = c / 40;
        int cc = (c - r * 40) * 8;
        *(half8*)&Wlds[r][cc] = *(const half8*)(w2h + r * NP + cc);
    }
    __syncthreads();

    const int m0 = blockIdx.x * 64 + wave * 16;
    const _Float16* hp = h + (size_t)(m0 + row15) * NP + quad * 8;
    floatx4 acc = {};
#pragma unroll
    for (int kk = 0; kk < NP; kk += 32) {
        half8 a2 = *(const half8*)(hp + kk);
        half8 b2 = *(const half8*)&Wlds[row15][kk + quad * 8];
        acc = __builtin_amdgcn_mfma_f32_16x16x32_f16(a2, b2, acc, 0, 0, 0);
    }
    float s = 0.f, q = 0.f;
#pragma unroll
    for (int r = 0; r < 4; ++r) {
        float v = acc[r];
        oc[(size_t)(m0 + quad * 4 + r) * NP2 + row15] = v;
        s += v; q += v * v;
    }
    s += __shfl_xor(s, 16); s += __shfl_xor(s, 32);
    q += __shfl_xor(q, 16); q += __shfl_xor(q, 32);
    if (lane < 16) { reds[wave][row15] = s; redq[wave][row15] = q; }
    __syncthreads();
    if (t < 16) {
        float S = reds[0][t] + reds[1][t] + reds[2][t] + reds[3][t];
        float Q = redq[0][t] + redq[1][t] + redq[2][t] + redq[3][t];
        part2[(size_t)t * NBLK + blockIdx.x]          = S;
        part2[(size_t)(16 + t) * NBLK + blockIdx.x]   = Q;
    }
}

// ---------------- K4: FUSED reduce#2 + BN2-coefficient precompute
__global__ void k_stat2(const float* __restrict__ part2, const float* __restrict__ gamma2,
                        float* __restrict__ st2)
{
    __shared__ float redS[4], redQ[4];
    const int k = blockIdx.x;            // 0..15
    const int t = threadIdx.x;           // 256
    const float* ps = part2 + (size_t)k * NBLK;
    const float* pq = part2 + (size_t)(16 + k) * NBLK;
    float s = ps[t] + ps[t + 256] + ps[t + 512] + ps[t + 768];
    float q = pq[t] + pq[t + 256] + pq[t + 512] + pq[t + 768];
#pragma unroll
    for (int off = 1; off < 64; off <<= 1) {
        s += __shfl_xor(s, off);
        q += __shfl_xor(q, off);
    }
    if ((t & 63) == 0) { redS[t >> 6] = s; redQ[t >> 6] = q; }
    __syncthreads();
    if (t == 0) {
        float S = redS[0] + redS[1] + redS[2] + redS[3];
        float Q = redQ[0] + redQ[1] + redQ[2] + redQ[3];
        float mean = S * (1.0f / 65536.0f);
        float var  = Q * (1.0f / 65536.0f) - mean * mean;
        float sc   = (k < D_OUT) ? gamma2[k] / sqrtf(var + EPS) : 0.0f;
        st2[k]      = mean;
        st2[16 + k] = sc;
    }
}

// ---------------- K5: BN2 epilogue -> out[65536][10] fp32
__global__ void k_final(const float* __restrict__ oc, const float* __restrict__ st2,
                        const float* __restrict__ beta2, float* __restrict__ out)
{
    int idx = blockIdx.x * 256 + threadIdx.x;    // 2560*256 == 655360 exactly
    int m = idx / 10;
    int k = idx - m * 10;
    float mean = st2[k];
    float sc   = st2[16 + k];
    out[idx] = (oc[(size_t)m * NP2 + k] - mean) * sc + beta2[k];
}

extern "C" void kernel_launch(void* const* d_in, const int* in_sizes, int n_in,
                              void* d_out, int out_size, void* d_ws, size_t ws_size,
                              hipStream_t stream)
{
    const float* x      = (const float*)d_in[0];
    const float* W1     = (const float*)d_in[1];
    const float* gamma1 = (const float*)d_in[2];
    // d_in[3] = beta1 : algebraically cancels under BN2's mean subtraction
    const float* W2     = (const float*)d_in[4];
    const float* gamma2 = (const float*)d_in[5];
    const float* beta2  = (const float*)d_in[6];
    float* out = (float*)d_out;

    char* ws = (char*)d_ws;
    _Float16* S1    = (_Float16*)(ws + OFF_S1);
    _Float16* h     = (_Float16*)(ws + OFF_H);
    _Float16* w2h   = (_Float16*)(ws + OFF_W2);
    float*    st2   = (float*)(ws + OFF_ST2);
    float*    oc    = (float*)(ws + OFF_OC);
    float*    part  = (float*)(ws + OFF_P1);   // aliases oc (time-disjoint)
    float*    part2 = (float*)(ws + OFF_P2);

    k_prep1 <<<1000, 256, 0, stream>>>(W1, S1);
    k_gemm1 <<<NBLK, 256, 0, stream>>>(x, S1, h, part);
    k_stat1 <<<320, 256, 0, stream>>>(part, gamma1, W2, w2h);
    k_gemm2 <<<NBLK, 256, 0, stream>>>(h, w2h, oc, part2);
    k_stat2 <<<16, 256, 0, stream>>>(part2, gamma2, st2);
    k_final <<<2560, 256, 0, stream>>>(oc, st2, beta2, out);
}

// Round 8
// 91.287 us; speedup vs baseline: 1.2094x; 1.1514x over previous
//
#include <hip/hip_runtime.h>
#include <cstdint>
#include <cstddef>

// Problem dims
#define B_ROWS 65536
#define D_IN   784
#define KP     800      // D_IN padded to multiple of 32
#define D_H    300
#define NP     320      // D_H padded to multiple of 64
#define D_OUT  10
#define NP2    16       // D_OUT padded to 16
#define EPS    1e-5f
#define NBLK   1024     // blocks in gemm1 and gemm2 grids

typedef _Float16 half8  __attribute__((ext_vector_type(8)));
typedef float    floatx4 __attribute__((ext_vector_type(4)));

// Workspace layout (bytes). part[] aliases oc[]: part is consumed by k_stat1
// BEFORE k_gemm2 writes oc (strictly ordered on one stream).
#define OFF_S1   ((size_t)0)                       // _Float16[320*800]   = 512000
#define OFF_H    ((size_t)512000)                  // _Float16[65536*320] = 41943040
#define OFF_ZB   (OFF_H + (size_t)41943040)        // float[16] zero block (in old ST1 slot)
#define OFF_W2   (OFF_ZB + (size_t)2560)           // _Float16[16*320]    = 10240
#define OFF_ST2  (OFF_W2 + (size_t)10240)          // float[32]
#define OFF_OC   (OFF_ST2 + (size_t)256)           // float[65536*16]     = 4194304
#define OFF_P1   OFF_OC                            // float[640][1024] (alias, time-disjoint)
#define OFF_P2   (OFF_OC + (size_t)4194304)        // float[32][1024]     = 131072

// ---------------- K0: binarize W1 -> fp16 (+-1), zero-padded to [320][800]
// Also zeroes the 64B pad-source block used by k_gemm1's tail DMA redirect.
__global__ void k_prep1(const float* __restrict__ W1, _Float16* __restrict__ S1,
                        float* __restrict__ zb)
{
    if (blockIdx.x == 0 && threadIdx.x < 16) zb[threadIdx.x] = 0.0f;
    int idx = blockIdx.x * 256 + threadIdx.x;      // 0..255999
    int n = idx / KP;
    int k = idx - n * KP;
    float v = 0.0f;
    if (n < D_H && k < D_IN)
        v = (W1[n * D_IN + k] >= 0.0f) ? 1.0f : -1.0f;
    S1[idx] = (_Float16)v;
}

// ---------------- K1: h = x @ S1^T  (M=65536, N=320, K=800), fp16 MFMA
// GLOBAL_LOAD_LDS variant (m97 staging pattern, the one untried lever).
// A-tile [64][32] fp32 DMA'd straight to LDS (no VGPR round-trip, no
// ds_write, no lgkm dependency at the barrier): 2x 16B global_load_lds per
// thread issued at the TOP of step s for step s+1's buffer; the end-of-step
// barrier uses a COUNTED s_waitcnt vmcnt(5) that drains only the 2 DMA
// loads while leaving the 5 B-prefetch loads of step s+1 in flight.
// fp32->fp16 cvt moves to the fragment-read side (VALUBusy has headroom).
// LDS stride is 128B (32-way hazard) -> per rule 21: linear DMA dest +
// INVERSE-swizzled per-lane global source + swizzled read. Storage chunk sc
// of row r holds logical 16B-chunk sc^(r&7); reads XOR the same way ->
// uniform 8 lanes/chunk across banks. K-pad tail (cols 784..799, step 24)
// redirects affected lanes' source pointers to a zeroed 64B block.
// Numerics: same RTNE cvt values, same MFMA order -> bit-identical.
// B register ping-pong kept (R7 proved single-buffer B regresses).

typedef const __attribute__((address_space(1))) void* gas_p;
typedef __attribute__((address_space(3))) void* las_p;

__device__ __forceinline__ void gload_lds16(const float* g, float* l)
{
    __builtin_amdgcn_global_load_lds((gas_p)g, (las_p)l, 16, 0, 0);
}

#define PF_B(BV, NK)                                                        \
    _Pragma("unroll")                                                       \
    for (int nt = 0; nt < 5; ++nt)                                          \
        BV[nt] = *(const half8*)(bb + (size_t)nt * 16 * KP + (NK));

#define ISSUE_A(BUF, KK)                                                    \
    gload_lds16(gA0 + (KK), &Afl[BUF][0][0] + lof);                         \
    gload_lds16(gA1 + (KK), &Afl[BUF][0][0] + 1024 + lof);

#define ISSUE_A_TAIL(BUF)                                                   \
    gload_lds16(ts0, &Afl[BUF][0][0] + lof);                                \
    gload_lds16(ts1, &Afl[BUF][0][0] + 1024 + lof);

// read swizzled chunks ce=(2q)^e, co=ce^1 of row mt*16+row15, cvt to half8
#define AFRAGF(BUF)                                                         \
    _Pragma("unroll")                                                       \
    for (int mt = 0; mt < 4; ++mt) {                                        \
        floatx4 f0 = *(const floatx4*)&Afl[BUF][mt * 16 + row15][ce * 4];   \
        floatx4 f1 = *(const floatx4*)&Afl[BUF][mt * 16 + row15][co * 4];   \
        half8 hv;                                                           \
        _Pragma("unroll")                                                   \
        for (int j = 0; j < 4; ++j) {                                       \
            hv[j]     = (_Float16)f0[j];                                    \
            hv[4 + j] = (_Float16)f1[j];                                    \
        }                                                                   \
        a[mt] = hv;                                                         \
    }

#define COMPUTE(BV)                                                         \
    _Pragma("unroll")                                                       \
    for (int nt = 0; nt < 5; ++nt)                                          \
        _Pragma("unroll")                                                   \
        for (int mt = 0; mt < 4; ++mt)                                      \
            acc[mt][nt] = __builtin_amdgcn_mfma_f32_16x16x32_f16(           \
                a[mt], BV[nt], acc[mt][nt], 0, 0, 0);

// counted drain: waits the 2 A-DMA loads (oldest), leaves 5 B loads in
// flight across the barrier. sched_barrier(0) pins issue order (rule 18).
#define STEP_SYNC()                                                         \
    __builtin_amdgcn_sched_barrier(0);                                      \
    asm volatile("s_waitcnt vmcnt(5)" ::: "memory");                        \
    __builtin_amdgcn_sched_barrier(0);                                      \
    __builtin_amdgcn_s_barrier();                                           \
    __builtin_amdgcn_sched_barrier(0);

__global__ __launch_bounds__(256) void k_gemm1(const float* __restrict__ x,
                                               const _Float16* __restrict__ S1,
                                               _Float16* __restrict__ h,
                                               float* __restrict__ part,
                                               const float* __restrict__ zb)
{
    __shared__ __align__(16) float Afl[2][64][32];   // 2 x 8 KB
    const int t     = threadIdx.x;
    const int wave  = t >> 6;
    const int lane  = t & 63;
    const int row15 = lane & 15;
    const int quad  = lane >> 4;
    const int m0    = blockIdx.x * 64;

    // DMA staging: slot = wave*64+lane (call0) / +256 (call1); row = slot>>3,
    // storage chunk = slot&7, source chunk = (slot&7)^(row&7).
    const int rA   = wave * 8 + (lane >> 3);          // call0 row (call1: +32)
    const int cswz = (lane & 7) ^ ((lane >> 3) & 7);  // swizzled source chunk
    const int lof  = wave * 256;                      // LDS float offset, call0
    const float* gA0 = x + (size_t)(m0 + rA) * D_IN + cswz * 4;
    const float* gA1 = gA0 + (size_t)32 * D_IN;
    // tail step (kk=768): cols 768+cswz*4 >= 784 for cswz>=4 -> zero block
    const float* ts0 = (cswz >= 4) ? zb : (gA0 + 768);
    const float* ts1 = (cswz >= 4) ? zb : (gA1 + 768);

    // fragment-read swizzle (e = row15&7 since (mt*16)&7 == 0)
    const int ce = (2 * quad) ^ (row15 & 7);
    const int co = ce ^ 1;

    // B fragment base (MFMA B layout: lane holds col=row15, k=quad*8..+8)
    const _Float16* bb = S1 + (size_t)(wave * 80 + row15) * KP + quad * 8;

    floatx4 acc[4][5] = {};
    half8   b0[5], b1[5];
    half8   a[4];

    // prologue: DMA A(0)->buf0; b0 <- B(0); counted drain; barrier
    ISSUE_A(0, 0)
    __builtin_amdgcn_sched_barrier(0);
    PF_B(b0, 0)
    STEP_SYNC()

    for (int i = 0; i < 12; ++i) {
        const int kk = i * 64;
        // even step s=2i: computes buf0/b0; DMA A(s+1)->buf1; prefetch b1
        ISSUE_A(1, kk + 32)
        __builtin_amdgcn_sched_barrier(0);
        PF_B(b1, kk + 32)
        AFRAGF(0)
        COMPUTE(b0)
        STEP_SYNC()
        // odd step s=2i+1: computes buf1/b1; DMA A(s+2)->buf0; prefetch b0
        if (i < 11) { ISSUE_A(0, kk + 64) } else { ISSUE_A_TAIL(0) }
        __builtin_amdgcn_sched_barrier(0);
        PF_B(b0, kk + 64)              // i=11 -> B(24) at koff 768
        AFRAGF(1)
        COMPUTE(b1)
        STEP_SYNC()
    }
    // tail step 24: buf0/b0 (k = 768..799; pad cols are zeros both sides)
    AFRAGF(0)
    COMPUTE(b0)

    // --- epilogue: store h (C/D layout: col=lane&15, row=quad*4+r) + stats
    float s[5] = {}, q[5] = {};
#pragma unroll
    for (int mt = 0; mt < 4; ++mt)
#pragma unroll
        for (int nt = 0; nt < 5; ++nt)
#pragma unroll
            for (int r = 0; r < 4; ++r) {
                float v = acc[mt][nt][r];
                int m = m0 + mt * 16 + quad * 4 + r;
                int n = wave * 80 + nt * 16 + row15;
                h[(size_t)m * NP + n] = (_Float16)v;
                s[nt] += v;
                q[nt] += v * v;
            }
    // reduce over quad (waves own disjoint col ranges -> no cross-wave combine)
#pragma unroll
    for (int nt = 0; nt < 5; ++nt) {
        s[nt] += __shfl_xor(s[nt], 16); s[nt] += __shfl_xor(s[nt], 32);
        q[nt] += __shfl_xor(q[nt], 16); q[nt] += __shfl_xor(q[nt], 32);
    }
    if (quad == 0) {
#pragma unroll
        for (int nt = 0; nt < 5; ++nt) {
            int col = wave * 80 + nt * 16 + row15;
            part[(size_t)col * NBLK + blockIdx.x]        = s[nt];
            part[(size_t)(NP + col) * NBLK + blockIdx.x] = q[nt];
        }
    }
}

// ---------------- K2: FUSED reduce + BN1-fold-into-W2
// One block per hidden col j: reduce sum AND sumsq partials, then threads
// 0..15 write the BN1-scaled binarized W2 column.
__global__ void k_stat1(const float* __restrict__ part, const float* __restrict__ gamma1,
                        const float* __restrict__ W2, _Float16* __restrict__ w2h)
{
    __shared__ float redS[4], redQ[4];
    const int j = blockIdx.x;            // 0..319
    const int t = threadIdx.x;           // 256
    const float* ps = part + (size_t)j * NBLK;
    const float* pq = part + (size_t)(NP + j) * NBLK;
    float s = ps[t] + ps[t + 256] + ps[t + 512] + ps[t + 768];
    float q = pq[t] + pq[t + 256] + pq[t + 512] + pq[t + 768];
#pragma unroll
    for (int off = 1; off < 64; off <<= 1) {
        s += __shfl_xor(s, off);
        q += __shfl_xor(q, off);
    }
    if ((t & 63) == 0) { redS[t >> 6] = s; redQ[t >> 6] = q; }
    __syncthreads();
    if (t < NP2) {
        float S = redS[0] + redS[1] + redS[2] + redS[3];
        float Q = redQ[0] + redQ[1] + redQ[2] + redQ[3];
        float mean = S * (1.0f / 65536.0f);
        float var  = Q * (1.0f / 65536.0f) - mean * mean;
        float a1   = 0.0f;
        if (j < D_H) a1 = gamma1[j] / sqrtf(var + EPS);
        float w = 0.0f;
        if (t < D_OUT && j < D_H)
            w = (W2[t * D_H + j] >= 0.0f) ? a1 : -a1;
        w2h[t * NP + j] = (_Float16)w;
    }
}

// ---------------- K3: oc = h @ w2h^T  (K=320, N=16) + per-block stat partials
__global__ __launch_bounds__(256) void k_gemm2(const _Float16* __restrict__ h,
                                               const _Float16* __restrict__ w2h,
                                               float* __restrict__ oc,
                                               float* __restrict__ part2)
{
    __shared__ _Float16 Wlds[16][328];   // pad 320->328 to break bank conflicts
    __shared__ float reds[4][16], redq[4][16];
    const int t     = threadIdx.x;
    const int wave  = t >> 6;
    const int lane  = t & 63;
    const int row15 = lane & 15;
    const int quad  = lane >> 4;

    for (int c = t; c < 640; c += 256) { // 16*320/8 chunks
        int r  = c / 40;
        int cc = (c - r * 40) * 8;
        *(half8*)&Wlds[r][cc] = *(const half8*)(w2h + r * NP + cc);
    }
    __syncthreads();

    const int m0 = blockIdx.x * 64 + wave * 16;
    const _Float16* hp = h + (size_t)(m0 + row15) * NP + quad * 8;
    floatx4 acc = {};
#pragma unroll
    for (int kk = 0; kk < NP; kk += 32) {
        half8 a2 = *(const half8*)(hp + kk);
        half8 b2 = *(const half8*)&Wlds[row15][kk + quad * 8];
        acc = __builtin_amdgcn_mfma_f32_16x16x32_f16(a2, b2, acc, 0, 0, 0);
    }
    float s = 0.f, q = 0.f;
#pragma unroll
    for (int r = 0; r < 4; ++r) {
        float v = acc[r];
        oc[(size_t)(m0 + quad * 4 + r) * NP2 + row15] = v;
        s += v; q += v * v;
    }
    s += __shfl_xor(s, 16); s += __shfl_xor(s, 32);
    q += __shfl_xor(q, 16); q += __shfl_xor(q, 32);
    if (lane < 16) { reds[wave][row15] = s; redq[wave][row15] = q; }
    __syncthreads();
    if (t < 16) {
        float S = reds[0][t] + reds[1][t] + reds[2][t] + reds[3][t];
        float Q = redq[0][t] + redq[1][t] + redq[2][t] + redq[3][t];
        part2[(size_t)t * NBLK + blockIdx.x]          = S;
        part2[(size_t)(16 + t) * NBLK + blockIdx.x]   = Q;
    }
}

// ---------------- K4: FUSED reduce#2 + BN2-coefficient precompute
__global__ void k_stat2(const float* __restrict__ part2, const float* __restrict__ gamma2,
                        float* __restrict__ st2)
{
    __shared__ float redS[4], redQ[4];
    const int k = blockIdx.x;            // 0..15
    const int t = threadIdx.x;           // 256
    const float* ps = part2 + (size_t)k * NBLK;
    const float* pq = part2 + (size_t)(16 + k) * NBLK;
    float s = ps[t] + ps[t + 256] + ps[t + 512] + ps[t + 768];
    float q = pq[t] + pq[t + 256] + pq[t + 512] + pq[t + 768];
#pragma unroll
    for (int off = 1; off < 64; off <<= 1) {
        s += __shfl_xor(s, off);
        q += __shfl_xor(q, off);
    }
    if ((t & 63) == 0) { redS[t >> 6] = s; redQ[t >> 6] = q; }
    __syncthreads();
    if (t == 0) {
        float S = redS[0] + redS[1] + redS[2] + redS[3];
        float Q = redQ[0] + redQ[1] + redQ[2] + redQ[3];
        float mean = S * (1.0f / 65536.0f);
        float var  = Q * (1.0f / 65536.0f) - mean * mean;
        float sc   = (k < D_OUT) ? gamma2[k] / sqrtf(var + EPS) : 0.0f;
        st2[k]      = mean;
        st2[16 + k] = sc;
    }
}

// ---------------- K5: BN2 epilogue -> out[65536][10] fp32
__global__ void k_final(const float* __restrict__ oc, const float* __restrict__ st2,
                        const float* __restrict__ beta2, float* __restrict__ out)
{
    int idx = blockIdx.x * 256 + threadIdx.x;    // 2560*256 == 655360 exactly
    int m = idx / 10;
    int k = idx - m * 10;
    float mean = st2[k];
    float sc   = st2[16 + k];
    out[idx] = (oc[(size_t)m * NP2 + k] - mean) * sc + beta2[k];
}

extern "C" void kernel_launch(void* const* d_in, const int* in_sizes, int n_in,
                              void* d_out, int out_size, void* d_ws, size_t ws_size,
                              hipStream_t stream)
{
    const float* x      = (const float*)d_in[0];
    const float* W1     = (const float*)d_in[1];
    const float* gamma1 = (const float*)d_in[2];
    // d_in[3] = beta1 : algebraically cancels under BN2's mean subtraction
    const float* W2     = (const float*)d_in[4];
    const float* gamma2 = (const float*)d_in[5];
    const float* beta2  = (const float*)d_in[6];
    float* out = (float*)d_out;

    char* ws = (char*)d_ws;
    _Float16* S1    = (_Float16*)(ws + OFF_S1);
    _Float16* h     = (_Float16*)(ws + OFF_H);
    float*    zb    = (float*)(ws + OFF_ZB);
    _Float16* w2h   = (_Float16*)(ws + OFF_W2);
    float*    st2   = (float*)(ws + OFF_ST2);
    float*    oc    = (float*)(ws + OFF_OC);
    float*    part  = (float*)(ws + OFF_P1);   // aliases oc (time-disjoint)
    float*    part2 = (float*)(ws + OFF_P2);

    k_prep1 <<<1000, 256, 0, stream>>>(W1, S1, zb);
    k_gemm1 <<<NBLK, 256, 0, stream>>>(x, S1, h, part, zb);
    k_stat1 <<<320, 256, 0, stream>>>(part, gamma1, W2, w2h);
    k_gemm2 <<<NBLK, 256, 0, stream>>>(h, w2h, oc, part2);
    k_stat2 <<<16, 256, 0, stream>>>(part2, gamma2, st2);
    k_final <<<2560, 256, 0, stream>>>(oc, st2, beta2, out);
}